// Round 1
// baseline (71.686 us; speedup 1.0000x reference)
//
#include <hip/hip_runtime.h>
#include <hip/hip_bf16.h>

// Problem constants (match reference.py)
#define BB 32
#define SS 2048
#define DD 768
#define WW 1024

// One wave (64 lanes) per (batch, word). word_ids is sorted per batch row, so
// the subwords of word w occupy a contiguous range found by binary search.
// Each lane owns 3 float4 slots of the 768-float embedding (64*4*3 = 768).
__global__ __launch_bounds__(256) void mean_pool_words_kernel(
    const float* __restrict__ hid,   // [B, S, D]
    const int*   __restrict__ wid,   // [B, S] sorted per row
    float*       __restrict__ X,     // [B, W, D]
    float*       __restrict__ mask)  // [B, W] as 0.0/1.0
{
    const int wave = threadIdx.x >> 6;      // 0..3
    const int lane = threadIdx.x & 63;
    const long gw = (long)blockIdx.x * 4 + wave;   // global word id in [0, B*W)
    const int b = (int)(gw >> 10);          // / W
    const int w = (int)(gw & (WW - 1));     // % W

    const int* ids = wid + (long)b * SS;

    // lower_bound(w)
    int lo = 0, hi = SS;
    while (lo < hi) { int mid = (lo + hi) >> 1; if (ids[mid] < w) lo = mid + 1; else hi = mid; }
    const int start = lo;
    // lower_bound(w+1), continuing from start
    hi = SS;
    while (lo < hi) { int mid = (lo + hi) >> 1; if (ids[mid] < w + 1) lo = mid + 1; else hi = mid; }
    const int end = lo;
    const int cnt = end - start;

    float a0x = 0.f, a0y = 0.f, a0z = 0.f, a0w = 0.f;
    float a1x = 0.f, a1y = 0.f, a1z = 0.f, a1w = 0.f;
    float a2x = 0.f, a2y = 0.f, a2z = 0.f, a2w = 0.f;

    const float4* src = (const float4*)(hid + (long)b * SS * DD);
    for (int s = start; s < end; ++s) {
        const float4* row = src + (long)s * (DD / 4);
        float4 v0 = row[lane];
        float4 v1 = row[lane + 64];
        float4 v2 = row[lane + 128];
        a0x += v0.x; a0y += v0.y; a0z += v0.z; a0w += v0.w;
        a1x += v1.x; a1y += v1.y; a1z += v1.z; a1w += v1.w;
        a2x += v2.x; a2y += v2.y; a2z += v2.z; a2w += v2.w;
    }

    const float scale = (cnt > 0) ? (1.0f / (float)cnt) : 0.0f;

    float4* dst = (float4*)(X + ((long)b * WW + w) * DD);
    float4 o0, o1, o2;
    o0.x = a0x * scale; o0.y = a0y * scale; o0.z = a0z * scale; o0.w = a0w * scale;
    o1.x = a1x * scale; o1.y = a1y * scale; o1.z = a1z * scale; o1.w = a1w * scale;
    o2.x = a2x * scale; o2.y = a2y * scale; o2.z = a2z * scale; o2.w = a2w * scale;
    dst[lane]       = o0;
    dst[lane + 64]  = o1;
    dst[lane + 128] = o2;

    if (lane == 0) {
        mask[(long)b * WW + w] = (cnt > 0) ? 1.0f : 0.0f;
    }
}

extern "C" void kernel_launch(void* const* d_in, const int* in_sizes, int n_in,
                              void* d_out, int out_size, void* d_ws, size_t ws_size,
                              hipStream_t stream) {
    const float* hid = (const float*)d_in[0];   // [B,S,D] float32
    const int*   wid = (const int*)d_in[1];     // [B,S] int32

    float* X    = (float*)d_out;                // [B,W,D] flat first
    float* mask = X + (long)BB * WW * DD;       // [B,W] after it

    const int n_words = BB * WW;                // 32768
    const int blocks  = n_words / 4;            // 4 words (waves) per 256-thread block
    mean_pool_words_kernel<<<blocks, 256, 0, stream>>>(hid, wid, X, mask);
}

// Round 2
// 57.196 us; speedup vs baseline: 1.2533x; 1.2533x over previous
//
#include <hip/hip_runtime.h>
#include <hip/hip_bf16.h>

// Problem constants (match reference.py)
#define BB 32
#define SS 2048
#define DD 768
#define WW 1024

// Kernel 1: boundary detection. One thread per (b, s) subword.
// Builds startLB[b][v] = lower_bound of v in the sorted row wid[b, :], for
// v in [0, W] (inclusive sentinel). Every entry is written exactly once per
// call (gap-filling covers empty words), so no memset of the workspace is
// needed. Also writes mask[b][v] (1.0 iff word v has >=1 subword).
__global__ __launch_bounds__(256) void boundaries_kernel(
    const int* __restrict__ wid,      // [B, S] sorted per row
    int*       __restrict__ startLB,  // [B, W+1]
    float*     __restrict__ mask)     // [B, W]
{
    const int t = blockIdx.x * 256 + threadIdx.x;   // [0, B*S)
    const int b = t >> 11;                          // / S
    const int s = t & (SS - 1);                     // % S

    const int* ids = wid + (long)b * SS;
    const int w = ids[s];
    const int p = (s == 0) ? -1 : ids[s - 1];

    int*   sl = startLB + (long)b * (WW + 1);
    float* mk = mask + (long)b * WW;

    // This thread is the unique writer for words v in (p, w].
    for (int v = p + 1; v <= w; ++v) {
        sl[v] = s;
        mk[v] = (v == w) ? 1.0f : 0.0f;   // gap words (v<w) are empty
    }
    // Tail: words beyond the last id are empty; write the sentinel.
    if (s == SS - 1) {
        for (int v = w + 1; v <= WW; ++v) {
            sl[v] = SS;
            if (v < WW) mk[v] = 0.0f;
        }
    }
}

// Kernel 2: streaming mean-pool. One wave (64 lanes) per (batch, word).
// Range comes from two independent L2-hot loads instead of binary search.
// Each lane owns 3 float4 slots of the 768-float embedding (64*4*3 = 768).
__global__ __launch_bounds__(256) void mean_pool_words_kernel(
    const float* __restrict__ hid,      // [B, S, D]
    const int*   __restrict__ startLB,  // [B, W+1]
    float*       __restrict__ X)        // [B, W, D]
{
    const int wave = threadIdx.x >> 6;      // 0..3
    const int lane = threadIdx.x & 63;
    const long gw = (long)blockIdx.x * 4 + wave;   // global word id in [0, B*W)
    const int b = (int)(gw >> 10);          // / W
    const int w = (int)(gw & (WW - 1));     // % W

    const int* sl = startLB + (long)b * (WW + 1) + w;
    const int start = sl[0];
    const int end   = sl[1];
    const int cnt   = end - start;

    float a0x = 0.f, a0y = 0.f, a0z = 0.f, a0w = 0.f;
    float a1x = 0.f, a1y = 0.f, a1z = 0.f, a1w = 0.f;
    float a2x = 0.f, a2y = 0.f, a2z = 0.f, a2w = 0.f;

    const float4* src = (const float4*)(hid + (long)b * SS * DD);
    for (int s = start; s < end; ++s) {
        const float4* row = src + (long)s * (DD / 4);
        float4 v0 = row[lane];
        float4 v1 = row[lane + 64];
        float4 v2 = row[lane + 128];
        a0x += v0.x; a0y += v0.y; a0z += v0.z; a0w += v0.w;
        a1x += v1.x; a1y += v1.y; a1z += v1.z; a1w += v1.w;
        a2x += v2.x; a2y += v2.y; a2z += v2.z; a2w += v2.w;
    }

    const float scale = (cnt > 0) ? (1.0f / (float)cnt) : 0.0f;

    float4* dst = (float4*)(X + ((long)b * WW + w) * DD);
    float4 o0, o1, o2;
    o0.x = a0x * scale; o0.y = a0y * scale; o0.z = a0z * scale; o0.w = a0w * scale;
    o1.x = a1x * scale; o1.y = a1y * scale; o1.z = a1z * scale; o1.w = a1w * scale;
    o2.x = a2x * scale; o2.y = a2y * scale; o2.z = a2z * scale; o2.w = a2w * scale;
    dst[lane]       = o0;
    dst[lane + 64]  = o1;
    dst[lane + 128] = o2;
}

extern "C" void kernel_launch(void* const* d_in, const int* in_sizes, int n_in,
                              void* d_out, int out_size, void* d_ws, size_t ws_size,
                              hipStream_t stream) {
    const float* hid = (const float*)d_in[0];   // [B,S,D] float32
    const int*   wid = (const int*)d_in[1];     // [B,S] int32

    float* X    = (float*)d_out;                // [B,W,D] flat first
    float* mask = X + (long)BB * WW * DD;       // [B,W] after it

    int* startLB = (int*)d_ws;                  // [B, W+1] = 131,200 bytes

    // Kernel 1: 64K threads, one per subword.
    boundaries_kernel<<<(BB * SS) / 256, 256, 0, stream>>>(wid, startLB, mask);

    // Kernel 2: one wave per word, 4 waves per block.
    const int n_words = BB * WW;                // 32768
    mean_pool_words_kernel<<<n_words / 4, 256, 0, stream>>>(hid, startLB, X);
}